// Round 2
// baseline (428.826 us; speedup 1.0000x reference)
//
#include <hip/hip_runtime.h>
#include <math.h>

constexpr int B_  = 2;
constexpr int N_  = 10000;
constexpr int E_  = 160000;
constexpr int H_  = 128;
constexpr int ET_ = 8;
constexpr float EPS_ = 1e-5f;
constexpr float RSQH = 0.08838834764831845f; // 1/sqrt(128)

// ---------------------------------------------------------------------------
// Per-node Q/K/V.  thread = output column j; x[node][k] is wave-uniform ->
// scalar loads (SMEM); inner loop is pure v_fma with one scalar operand.
// Weights loaded once per block (coalesced vector loads, L2-resident).
// ---------------------------------------------------------------------------
template<int NT>
__global__ __launch_bounds__(128)
void qkv_kernel(const float* __restrict__ hidden, const float* __restrict__ time_emb,
                const float* __restrict__ Wq, const float* __restrict__ bq,
                const float* __restrict__ Wk, const float* __restrict__ Wv,
                float* __restrict__ Q, float* __restrict__ K, float* __restrict__ V)
{
    const int j = threadIdx.x;
    const int base = blockIdx.x * NT;
    float aq[NT], ak[NT], av[NT];
#pragma unroll
    for (int m = 0; m < NT; ++m) { aq[m] = 0.f; ak[m] = 0.f; av[m] = 0.f; }
    for (int k = 0; k < H_; k += 4) {
        float wq0 = Wq[(k+0)*H_+j], wq1 = Wq[(k+1)*H_+j], wq2 = Wq[(k+2)*H_+j], wq3 = Wq[(k+3)*H_+j];
        float wk0 = Wk[(k+0)*H_+j], wk1 = Wk[(k+1)*H_+j], wk2 = Wk[(k+2)*H_+j], wk3 = Wk[(k+3)*H_+j];
        float wv0 = Wv[(k+0)*H_+j], wv1 = Wv[(k+1)*H_+j], wv2 = Wv[(k+2)*H_+j], wv3 = Wv[(k+3)*H_+j];
#pragma unroll
        for (int m = 0; m < NT; ++m) {
            const float* hp = hidden   + (base + m) * H_ + k;   // uniform -> s_load
            const float* tp = time_emb + (base + m) * H_ + k;   // uniform -> s_load
            float h0 = hp[0], h1 = hp[1], h2 = hp[2], h3 = hp[3];
            float x0 = h0 + tp[0], x1 = h1 + tp[1], x2 = h2 + tp[2], x3 = h3 + tp[3];
            aq[m] += x0*wq0 + x1*wq1 + x2*wq2 + x3*wq3;
            ak[m] += x0*wk0 + x1*wk1 + x2*wk2 + x3*wk3;
            av[m] += h0*wv0 + h1*wv1 + h2*wv2 + h3*wv3;
        }
    }
    const float bqj = bq[j];
#pragma unroll
    for (int m = 0; m < NT; ++m) {
        int node = base + m;
        Q[node*H_+j] = aq[m] + bqj;
        K[node*H_+j] = ak[m];
        V[node*H_+j] = av[m];
    }
}

// ---------------------------------------------------------------------------
// Per-edge-type tables: Kt[t]=edge_emb[t]@Wk+bk, Vt[t]=edge_emb[t]@Wv+bv,
// eb[t]=edge_emb[t]@We+be.
// ---------------------------------------------------------------------------
__global__ __launch_bounds__(128)
void edgetab_kernel(const float* __restrict__ edge_emb,
                    const float* __restrict__ Wk, const float* __restrict__ bk,
                    const float* __restrict__ Wv, const float* __restrict__ bv,
                    const float* __restrict__ We, const float* __restrict__ be,
                    float* __restrict__ Kt, float* __restrict__ Vt, float* __restrict__ eb)
{
    const int j = threadIdx.x;
    for (int t = 0; t < ET_; ++t) {
        float ak = bk[j], av = bv[j];
        for (int d = 0; d < H_; ++d) {
            float e = edge_emb[t*H_ + d];
            ak += e * Wk[d*H_ + j];
            av += e * Wv[d*H_ + j];
        }
        Kt[t*H_ + j] = ak;
        Vt[t*H_ + j] = av;
    }
    if (j < ET_) {
        float s = be[0];
        for (int d = 0; d < H_; ++d) s += edge_emb[j*H_ + d] * We[d];
        eb[j] = s;
    }
}

// ---------------------------------------------------------------------------
// CSR build: histogram, wave-shuffle scan, scatter.
// ---------------------------------------------------------------------------
__global__ void hist_kernel(const int* __restrict__ tgt, int* __restrict__ hist)
{
    int e = blockIdx.x * blockDim.x + threadIdx.x;
    if (e < E_) atomicAdd(&hist[tgt[e]], 1);
}

__global__ __launch_bounds__(1024)
void scan_kernel(const int* __restrict__ hist, int* __restrict__ offs, int* __restrict__ cursor)
{
    __shared__ int wpart[16];
    __shared__ int wexcl[16];
    __shared__ int carry_s;
    const int tid = threadIdx.x, wave = tid >> 6, lane = tid & 63;
    if (tid == 0) carry_s = 0;
    __syncthreads();
    for (int base = 0; base < N_; base += 1024) {
        int idx = base + tid;
        int v = (idx < N_) ? hist[idx] : 0;
        int s = v;
#pragma unroll
        for (int off = 1; off < 64; off <<= 1) {
            int t = __shfl_up(s, off);
            if (lane >= off) s += t;
        }
        if (lane == 63) wpart[wave] = s;
        __syncthreads();
        if (tid == 0) {
            int c = carry_s;
            for (int w = 0; w < 16; ++w) { int p = wpart[w]; wexcl[w] = c; c += p; }
            carry_s = c;
        }
        __syncthreads();
        if (idx < N_) {
            int excl = wexcl[wave] + s - v;
            offs[idx] = excl;
            cursor[idx] = excl;
        }
        __syncthreads();  // protect wpart/wexcl/carry_s for next chunk
    }
    if (threadIdx.x == 0) offs[N_] = carry_s;
}

__global__ void scatter_kernel(const int* __restrict__ src, const int* __restrict__ tgt,
                               const int* __restrict__ type, int* __restrict__ cursor,
                               int* __restrict__ sorted)
{
    int e = blockIdx.x * blockDim.x + threadIdx.x;
    if (e < E_) {
        int t = tgt[e];
        int pos = atomicAdd(&cursor[t], 1);
        sorted[pos] = src[e] | (type[e] << 16);
    }
}

// ---------------------------------------------------------------------------
// Attention: ONE WAVE per (b, target node), 4 nodes per 256-thread block.
// Online softmax, 2 edges in flight per iteration (independent shfl chains),
// no LDS, no __syncthreads.
// ---------------------------------------------------------------------------
__global__ __launch_bounds__(256)
void attn_kernel(const float* __restrict__ Q, const float* __restrict__ K,
                 const float* __restrict__ V, const float* __restrict__ Kt,
                 const float* __restrict__ Vt, const float* __restrict__ eb,
                 const int* __restrict__ offs, const int* __restrict__ sorted,
                 float* __restrict__ agg)
{
    const int bn = blockIdx.x * 4 + (threadIdx.x >> 6);   // b*N + n
    const int lane = threadIdx.x & 63;
    const int b = bn / N_;
    const int n = bn - b * N_;
    const int beg = offs[n], end = offs[n + 1];
    const int bbase = b * N_;

    const float2 q2 = *(const float2*)&Q[bn * H_ + 2 * lane];
    float m0 = -INFINITY, l0 = 0.f, a0x = 0.f, a0y = 0.f;
    float m1 = -INFINITY, l1 = 0.f, a1x = 0.f, a1y = 0.f;

    int i = beg;
    for (; i + 1 < end; i += 2) {
        int pkA = sorted[i], pkB = sorted[i + 1];
        int sA = pkA & 0xFFFF, tA = pkA >> 16;
        int sB = pkB & 0xFFFF, tB = pkB >> 16;
        float2 kA  = *(const float2*)&K [(bbase + sA) * H_ + 2 * lane];
        float2 kB  = *(const float2*)&K [(bbase + sB) * H_ + 2 * lane];
        float2 ktA = *(const float2*)&Kt[tA * H_ + 2 * lane];
        float2 ktB = *(const float2*)&Kt[tB * H_ + 2 * lane];
        float pA = q2.x * (kA.x + ktA.x) + q2.y * (kA.y + ktA.y);
        float pB = q2.x * (kB.x + ktB.x) + q2.y * (kB.y + ktB.y);
#pragma unroll
        for (int off = 32; off; off >>= 1) {
            pA += __shfl_xor(pA, off);
            pB += __shfl_xor(pB, off);
        }
        float logitA = pA * RSQH + eb[tA];
        float logitB = pB * RSQH + eb[tB];
        float2 vA  = *(const float2*)&V [(bbase + sA) * H_ + 2 * lane];
        float2 vB  = *(const float2*)&V [(bbase + sB) * H_ + 2 * lane];
        float2 vtA = *(const float2*)&Vt[tA * H_ + 2 * lane];
        float2 vtB = *(const float2*)&Vt[tB * H_ + 2 * lane];
        float nmA = fmaxf(m0, logitA);
        float scA = __expf(m0 - nmA);
        float pxA = __expf(logitA - nmA);
        l0 = l0 * scA + pxA;
        a0x = a0x * scA + pxA * (vA.x + vtA.x);
        a0y = a0y * scA + pxA * (vA.y + vtA.y);
        m0 = nmA;
        float nmB = fmaxf(m1, logitB);
        float scB = __expf(m1 - nmB);
        float pxB = __expf(logitB - nmB);
        l1 = l1 * scB + pxB;
        a1x = a1x * scB + pxB * (vB.x + vtB.x);
        a1y = a1y * scB + pxB * (vB.y + vtB.y);
        m1 = nmB;
    }
    if (i < end) {
        int pk = sorted[i];
        int s = pk & 0xFFFF, t = pk >> 16;
        float2 k2  = *(const float2*)&K [(bbase + s) * H_ + 2 * lane];
        float2 kt2 = *(const float2*)&Kt[t * H_ + 2 * lane];
        float part = q2.x * (k2.x + kt2.x) + q2.y * (k2.y + kt2.y);
#pragma unroll
        for (int off = 32; off; off >>= 1) part += __shfl_xor(part, off);
        float logit = part * RSQH + eb[t];
        float nm = fmaxf(m0, logit);
        float sc = __expf(m0 - nm);
        float px = __expf(logit - nm);
        float2 v2  = *(const float2*)&V [(bbase + s) * H_ + 2 * lane];
        float2 vt2 = *(const float2*)&Vt[t * H_ + 2 * lane];
        l0 = l0 * sc + px;
        a0x = a0x * sc + px * (v2.x + vt2.x);
        a0y = a0y * sc + px * (v2.y + vt2.y);
        m0 = nm;
    }

    float outx, outy;
    if (end == beg) {
        outx = 0.f; outy = 0.f;
    } else {
        float nm = fmaxf(m0, m1);
        float s0 = __expf(m0 - nm), s1 = __expf(m1 - nm);  // exp(-inf)=0 ok
        float L = l0 * s0 + l1 * s1;
        float invL = 1.f / L;
        outx = (a0x * s0 + a1x * s1) * invL;
        outy = (a0y * s0 + a1y * s1) * invL;
    }
    float2 o = make_float2(outx, outy);
    *(float2*)&agg[bn * H_ + 2 * lane] = o;
}

// ---------------------------------------------------------------------------
// MLP + residual + LayerNorm.  thread = column j; GEMM1 reads x scalar from
// global (uniform addresses), GEMM2 reads h1 from 8KB LDS (broadcast reads).
// ---------------------------------------------------------------------------
template<int NT>
__global__ __launch_bounds__(128)
void mlp_ln_kernel(const float* __restrict__ hidden, const float* __restrict__ agg,
                   const float* __restrict__ time_emb,
                   const float* __restrict__ W1, const float* __restrict__ b1,
                   const float* __restrict__ W2, const float* __restrict__ b2,
                   const float* __restrict__ gamma, const float* __restrict__ beta,
                   float* __restrict__ out)
{
    __shared__ float h1_s[NT][H_];
    __shared__ float red[2][NT][2];
    const int j = threadIdx.x;
    const int base = blockIdx.x * NT;
    const int wave = j >> 6, lane = j & 63;

    float acc[NT];
    const float b1j = b1[j];
#pragma unroll
    for (int m = 0; m < NT; ++m) acc[m] = b1j;

    const float* srcs[3] = { hidden, agg, time_emb };
#pragma unroll
    for (int s3 = 0; s3 < 3; ++s3) {
        const float* __restrict__ xp = srcs[s3];
        const float* __restrict__ wp = W1 + s3 * H_ * H_;
        for (int k = 0; k < H_; k += 4) {
            float w0 = wp[(k+0)*H_+j], w1 = wp[(k+1)*H_+j];
            float w2 = wp[(k+2)*H_+j], w3 = wp[(k+3)*H_+j];
#pragma unroll
            for (int m = 0; m < NT; ++m) {
                const float* p = xp + (base + m) * H_ + k;   // uniform -> s_load
                acc[m] += p[0]*w0 + p[1]*w1 + p[2]*w2 + p[3]*w3;
            }
        }
    }
#pragma unroll
    for (int m = 0; m < NT; ++m) {
        float v = acc[m];
        h1_s[m][j] = v / (1.f + __expf(-v));   // silu
    }
    __syncthreads();

    float acc2[NT];
    const float b2j = b2[j];
#pragma unroll
    for (int m = 0; m < NT; ++m) acc2[m] = b2j;
    for (int k = 0; k < H_; k += 4) {
        float w0 = W2[(k+0)*H_+j], w1 = W2[(k+1)*H_+j];
        float w2 = W2[(k+2)*H_+j], w3 = W2[(k+3)*H_+j];
#pragma unroll
        for (int m = 0; m < NT; ++m) {
            float4 h4 = *(const float4*)&h1_s[m][k];   // broadcast read
            acc2[m] += h4.x*w0 + h4.y*w1 + h4.z*w2 + h4.w*w3;
        }
    }

    // residual + LayerNorm
    float x[NT];
#pragma unroll
    for (int m = 0; m < NT; ++m)
        x[m] = hidden[(base + m) * H_ + j] + acc2[m];

#pragma unroll
    for (int m = 0; m < NT; ++m) {
        float s = x[m], q = x[m] * x[m];
#pragma unroll
        for (int off = 32; off; off >>= 1) {
            s += __shfl_xor(s, off);
            q += __shfl_xor(q, off);
        }
        if (lane == 0) { red[wave][m][0] = s; red[wave][m][1] = q; }
    }
    __syncthreads();
    const float gj = gamma[j], bj = beta[j];
#pragma unroll
    for (int m = 0; m < NT; ++m) {
        float S  = red[0][m][0] + red[1][m][0];
        float Q2 = red[0][m][1] + red[1][m][1];
        float mu  = S * (1.f / H_);
        float var = Q2 * (1.f / H_) - mu * mu;
        float rs  = rsqrtf(var + EPS_);
        out[(base + m) * H_ + j] = (x[m] - mu) * rs * gj + bj;
    }
}

// ---------------------------------------------------------------------------
extern "C" void kernel_launch(void* const* d_in, const int* in_sizes, int n_in,
                              void* d_out, int out_size, void* d_ws, size_t ws_size,
                              hipStream_t stream)
{
    const float* hidden   = (const float*)d_in[0];
    const float* time_emb = (const float*)d_in[1];
    const int*   eidx     = (const int*)d_in[2];
    const int*   etype    = (const int*)d_in[3];
    const float* edge_emb = (const float*)d_in[4];
    const float* Wq = (const float*)d_in[5];
    const float* bq = (const float*)d_in[6];
    const float* Wk = (const float*)d_in[7];
    const float* bk = (const float*)d_in[8];
    const float* Wv = (const float*)d_in[9];
    const float* bv = (const float*)d_in[10];
    const float* We = (const float*)d_in[11];
    const float* be = (const float*)d_in[12];
    const float* W1 = (const float*)d_in[13];
    const float* b1 = (const float*)d_in[14];
    const float* W2 = (const float*)d_in[15];
    const float* b2 = (const float*)d_in[16];
    const float* gamma = (const float*)d_in[17];
    const float* beta  = (const float*)d_in[18];
    float* out = (float*)d_out;

    constexpr int BNH = B_ * N_ * H_;
    float* Q   = (float*)d_ws;
    float* K   = Q + BNH;
    float* V   = K + BNH;
    float* agg = V + BNH;
    float* Kt  = agg + BNH;
    float* Vt  = Kt + ET_ * H_;
    float* ebt = Vt + ET_ * H_;
    int* hist   = (int*)(ebt + ET_);
    int* offs   = hist + N_;
    int* cursor = offs + (N_ + 1);
    int* sorted = cursor + N_;

    const int* esrc = eidx;
    const int* etgt = eidx + E_;

    hipMemsetAsync(hist, 0, N_ * sizeof(int), stream);

    qkv_kernel<16><<<(B_ * N_) / 16, 128, 0, stream>>>(hidden, time_emb, Wq, bq, Wk, Wv, Q, K, V);
    edgetab_kernel<<<1, 128, 0, stream>>>(edge_emb, Wk, bk, Wv, bv, We, be, Kt, Vt, ebt);
    hist_kernel<<<(E_ + 255) / 256, 256, 0, stream>>>(etgt, hist);
    scan_kernel<<<1, 1024, 0, stream>>>(hist, offs, cursor);
    scatter_kernel<<<(E_ + 255) / 256, 256, 0, stream>>>(esrc, etgt, etype, cursor, sorted);
    attn_kernel<<<(B_ * N_) / 4, 256, 0, stream>>>(Q, K, V, Kt, Vt, ebt, offs, sorted, agg);
    mlp_ln_kernel<16><<<(B_ * N_) / 16, 128, 0, stream>>>(hidden, agg, time_emb, W1, b1, W2, b2, gamma, beta, out);
}

// Round 3
// 256.849 us; speedup vs baseline: 1.6696x; 1.6696x over previous
//
#include <hip/hip_runtime.h>
#include <math.h>

constexpr int B_  = 2;
constexpr int N_  = 10000;
constexpr int E_  = 160000;
constexpr int H_  = 128;
constexpr int ET_ = 8;
constexpr float EPS_ = 1e-5f;
constexpr float RSQH = 0.08838834764831845f; // 1/sqrt(128)

typedef __bf16 bf16x8 __attribute__((ext_vector_type(8)));
typedef short  short8 __attribute__((ext_vector_type(8)));
typedef float  f32x4  __attribute__((ext_vector_type(4)));

__device__ inline unsigned short bf16b(float f) {
    return __builtin_bit_cast(unsigned short, (__bf16)f);
}

// ---------------------------------------------------------------------------
// Weight prep: f32 [K x 128] -> bf16 B-fragment-swizzled layout.
// Frag element for (kc, nt, lane, j): W[kc*32 + (lane>>4)*8 + j][nt*16 + (lane&15)]
// stored at dst[((kc*8+nt)*64 + lane)*8 + j].
// ---------------------------------------------------------------------------
__global__ __launch_bounds__(512)
void prep_w_kernel(const float* __restrict__ W1, const float* __restrict__ W2,
                   const float* __restrict__ Wq, const float* __restrict__ Wk,
                   const float* __restrict__ Wv,
                   unsigned short* __restrict__ W1s, unsigned short* __restrict__ W2s,
                   unsigned short* __restrict__ Wqs, unsigned short* __restrict__ Wks,
                   unsigned short* __restrict__ Wvs)
{
    int bid = blockIdx.x;
    const float* src; unsigned short* dst; int kc;
    if (bid < 12)      { src = W1; dst = W1s; kc = bid; }
    else if (bid < 16) { src = W2; dst = W2s; kc = bid - 12; }
    else if (bid < 20) { src = Wq; dst = Wqs; kc = bid - 16; }
    else if (bid < 24) { src = Wk; dst = Wks; kc = bid - 20; }
    else               { src = Wv; dst = Wvs; kc = bid - 24; }
    int nt = threadIdx.x >> 6, lane = threadIdx.x & 63;
    int q = lane >> 4, c = lane & 15;
    int kbase = kc * 32 + q * 8;
    int col = nt * 16 + c;
    unsigned short* out = dst + ((kc * 8 + nt) * 64 + lane) * 8;
#pragma unroll
    for (int j = 0; j < 8; ++j)
        out[j] = bf16b(src[(kbase + j) * H_ + col]);
}

__device__ inline bf16x8 ldfrag(const unsigned short* __restrict__ W, int kc, int nt, int lane) {
    short8 s = *(const short8*)(W + ((kc * 8 + nt) * 64 + lane) * 8);
    return __builtin_bit_cast(bf16x8, s);
}

// ---------------------------------------------------------------------------
// Q/K/V via MFMA.  One wave per 16-node M-tile; B-frags streamed from L2.
// Q=(h+t)@Wq+bq, K=(h+t)@Wk (bk folded into Kt), V=h@Wv (bv folded into Vt).
// ---------------------------------------------------------------------------
__global__ __launch_bounds__(256)
void qkv_mfma_kernel(const float* __restrict__ hidden, const float* __restrict__ time_emb,
                     const unsigned short* __restrict__ Wqs,
                     const unsigned short* __restrict__ Wks,
                     const unsigned short* __restrict__ Wvs,
                     const float* __restrict__ bq,
                     float* __restrict__ Q, float* __restrict__ K, float* __restrict__ V)
{
    const int wv = threadIdx.x >> 6, lane = threadIdx.x & 63;
    const int tile = blockIdx.x * 4 + wv;
    if (tile >= (B_ * N_) / 16) return;
    const int nbase = tile * 16;
    const int m = lane & 15, q = lane >> 4;
    const int koff = q * 8;

    bf16x8 aq[4], av[4];
    const float* hp = hidden   + (nbase + m) * H_ + koff;
    const float* tp = time_emb + (nbase + m) * H_ + koff;
#pragma unroll
    for (int kc = 0; kc < 4; ++kc) {
        float4 h0 = *(const float4*)(hp + kc * 32);
        float4 h1 = *(const float4*)(hp + kc * 32 + 4);
        float4 t0 = *(const float4*)(tp + kc * 32);
        float4 t1 = *(const float4*)(tp + kc * 32 + 4);
        bf16x8 fv, fq;
        fv[0]=(__bf16)h0.x; fv[1]=(__bf16)h0.y; fv[2]=(__bf16)h0.z; fv[3]=(__bf16)h0.w;
        fv[4]=(__bf16)h1.x; fv[5]=(__bf16)h1.y; fv[6]=(__bf16)h1.z; fv[7]=(__bf16)h1.w;
        fq[0]=(__bf16)(h0.x+t0.x); fq[1]=(__bf16)(h0.y+t0.y);
        fq[2]=(__bf16)(h0.z+t0.z); fq[3]=(__bf16)(h0.w+t0.w);
        fq[4]=(__bf16)(h1.x+t1.x); fq[5]=(__bf16)(h1.y+t1.y);
        fq[6]=(__bf16)(h1.z+t1.z); fq[7]=(__bf16)(h1.w+t1.w);
        av[kc] = fv; aq[kc] = fq;
    }

    f32x4 accq[8], acck[8], accv[8];
#pragma unroll
    for (int nt = 0; nt < 8; ++nt) { accq[nt] = (f32x4)0.f; acck[nt] = (f32x4)0.f; accv[nt] = (f32x4)0.f; }

#pragma unroll
    for (int kc = 0; kc < 4; ++kc) {
#pragma unroll
        for (int nt = 0; nt < 8; ++nt) {
            bf16x8 bfq = ldfrag(Wqs, kc, nt, lane);
            bf16x8 bfk = ldfrag(Wks, kc, nt, lane);
            bf16x8 bfv = ldfrag(Wvs, kc, nt, lane);
            accq[nt] = __builtin_amdgcn_mfma_f32_16x16x32_bf16(aq[kc], bfq, accq[nt], 0, 0, 0);
            acck[nt] = __builtin_amdgcn_mfma_f32_16x16x32_bf16(aq[kc], bfk, acck[nt], 0, 0, 0);
            accv[nt] = __builtin_amdgcn_mfma_f32_16x16x32_bf16(av[kc], bfv, accv[nt], 0, 0, 0);
        }
    }

#pragma unroll
    for (int nt = 0; nt < 8; ++nt) {
        int col = nt * 16 + m;
        float bqc = bq[col];
#pragma unroll
        for (int r = 0; r < 4; ++r) {
            int node = nbase + q * 4 + r;
            Q[node * H_ + col] = accq[nt][r] + bqc;
            K[node * H_ + col] = acck[nt][r];
            V[node * H_ + col] = accv[nt][r];
        }
    }
}

// ---------------------------------------------------------------------------
// Per-edge-type tables: Kt[t]=edge_emb[t]@Wk+bk, Vt[t]=edge_emb[t]@Wv+bv,
// eb[t]=edge_emb[t]@We+be.  (f32 — tiny)
// ---------------------------------------------------------------------------
__global__ __launch_bounds__(128)
void edgetab_kernel(const float* __restrict__ edge_emb,
                    const float* __restrict__ Wk, const float* __restrict__ bk,
                    const float* __restrict__ Wv, const float* __restrict__ bv,
                    const float* __restrict__ We, const float* __restrict__ be,
                    float* __restrict__ Kt, float* __restrict__ Vt, float* __restrict__ eb)
{
    const int j = threadIdx.x;
    for (int t = 0; t < ET_; ++t) {
        float ak = bk[j], av = bv[j];
        for (int d = 0; d < H_; ++d) {
            float e = edge_emb[t*H_ + d];
            ak += e * Wk[d*H_ + j];
            av += e * Wv[d*H_ + j];
        }
        Kt[t*H_ + j] = ak;
        Vt[t*H_ + j] = av;
    }
    if (j < ET_) {
        float s = be[0];
        for (int d = 0; d < H_; ++d) s += edge_emb[j*H_ + d] * We[d];
        eb[j] = s;
    }
}

// ---------------------------------------------------------------------------
// CSR build: histogram, wave-shuffle scan, scatter.
// ---------------------------------------------------------------------------
__global__ void hist_kernel(const int* __restrict__ tgt, int* __restrict__ hist)
{
    int e = blockIdx.x * blockDim.x + threadIdx.x;
    if (e < E_) atomicAdd(&hist[tgt[e]], 1);
}

__global__ __launch_bounds__(1024)
void scan_kernel(const int* __restrict__ hist, int* __restrict__ offs, int* __restrict__ cursor)
{
    __shared__ int wpart[16];
    __shared__ int wexcl[16];
    __shared__ int carry_s;
    const int tid = threadIdx.x, wave = tid >> 6, lane = tid & 63;
    if (tid == 0) carry_s = 0;
    __syncthreads();
    for (int base = 0; base < N_; base += 1024) {
        int idx = base + tid;
        int v = (idx < N_) ? hist[idx] : 0;
        int s = v;
#pragma unroll
        for (int off = 1; off < 64; off <<= 1) {
            int t = __shfl_up(s, off);
            if (lane >= off) s += t;
        }
        if (lane == 63) wpart[wave] = s;
        __syncthreads();
        if (tid == 0) {
            int c = carry_s;
            for (int w = 0; w < 16; ++w) { int p = wpart[w]; wexcl[w] = c; c += p; }
            carry_s = c;
        }
        __syncthreads();
        if (idx < N_) {
            int excl = wexcl[wave] + s - v;
            offs[idx] = excl;
            cursor[idx] = excl;
        }
        __syncthreads();
    }
    if (threadIdx.x == 0) offs[N_] = carry_s;
}

__global__ void scatter_kernel(const int* __restrict__ src, const int* __restrict__ tgt,
                               const int* __restrict__ type, int* __restrict__ cursor,
                               int* __restrict__ sorted)
{
    int e = blockIdx.x * blockDim.x + threadIdx.x;
    if (e < E_) {
        int t = tgt[e];
        int pos = atomicAdd(&cursor[t], 1);
        sorted[pos] = src[e] | (type[e] << 16);
    }
}

// ---------------------------------------------------------------------------
// Attention: one wave per (b, target node), online softmax, no LDS/barriers.
// ---------------------------------------------------------------------------
__global__ __launch_bounds__(256)
void attn_kernel(const float* __restrict__ Q, const float* __restrict__ K,
                 const float* __restrict__ V, const float* __restrict__ Kt,
                 const float* __restrict__ Vt, const float* __restrict__ eb,
                 const int* __restrict__ offs, const int* __restrict__ sorted,
                 float* __restrict__ agg)
{
    const int bn = blockIdx.x * 4 + (threadIdx.x >> 6);   // b*N + n
    const int lane = threadIdx.x & 63;
    const int b = bn / N_;
    const int n = bn - b * N_;
    const int beg = offs[n], end = offs[n + 1];
    const int bbase = b * N_;

    const float2 q2 = *(const float2*)&Q[bn * H_ + 2 * lane];
    float m0 = -INFINITY, l0 = 0.f, a0x = 0.f, a0y = 0.f;
    float m1 = -INFINITY, l1 = 0.f, a1x = 0.f, a1y = 0.f;

    int i = beg;
    for (; i + 1 < end; i += 2) {
        int pkA = sorted[i], pkB = sorted[i + 1];
        int sA = pkA & 0xFFFF, tA = pkA >> 16;
        int sB = pkB & 0xFFFF, tB = pkB >> 16;
        float2 kA  = *(const float2*)&K [(bbase + sA) * H_ + 2 * lane];
        float2 kB  = *(const float2*)&K [(bbase + sB) * H_ + 2 * lane];
        float2 ktA = *(const float2*)&Kt[tA * H_ + 2 * lane];
        float2 ktB = *(const float2*)&Kt[tB * H_ + 2 * lane];
        float pA = q2.x * (kA.x + ktA.x) + q2.y * (kA.y + ktA.y);
        float pB = q2.x * (kB.x + ktB.x) + q2.y * (kB.y + ktB.y);
#pragma unroll
        for (int off = 32; off; off >>= 1) {
            pA += __shfl_xor(pA, off);
            pB += __shfl_xor(pB, off);
        }
        float logitA = pA * RSQH + eb[tA];
        float logitB = pB * RSQH + eb[tB];
        float2 vA  = *(const float2*)&V [(bbase + sA) * H_ + 2 * lane];
        float2 vB  = *(const float2*)&V [(bbase + sB) * H_ + 2 * lane];
        float2 vtA = *(const float2*)&Vt[tA * H_ + 2 * lane];
        float2 vtB = *(const float2*)&Vt[tB * H_ + 2 * lane];
        float nmA = fmaxf(m0, logitA);
        float scA = __expf(m0 - nmA);
        float pxA = __expf(logitA - nmA);
        l0 = l0 * scA + pxA;
        a0x = a0x * scA + pxA * (vA.x + vtA.x);
        a0y = a0y * scA + pxA * (vA.y + vtA.y);
        m0 = nmA;
        float nmB = fmaxf(m1, logitB);
        float scB = __expf(m1 - nmB);
        float pxB = __expf(logitB - nmB);
        l1 = l1 * scB + pxB;
        a1x = a1x * scB + pxB * (vB.x + vtB.x);
        a1y = a1y * scB + pxB * (vB.y + vtB.y);
        m1 = nmB;
    }
    if (i < end) {
        int pk = sorted[i];
        int s = pk & 0xFFFF, t = pk >> 16;
        float2 k2  = *(const float2*)&K [(bbase + s) * H_ + 2 * lane];
        float2 kt2 = *(const float2*)&Kt[t * H_ + 2 * lane];
        float part = q2.x * (k2.x + kt2.x) + q2.y * (k2.y + kt2.y);
#pragma unroll
        for (int off = 32; off; off >>= 1) part += __shfl_xor(part, off);
        float logit = part * RSQH + eb[t];
        float nm = fmaxf(m0, logit);
        float sc = __expf(m0 - nm);
        float px = __expf(logit - nm);
        float2 v2  = *(const float2*)&V [(bbase + s) * H_ + 2 * lane];
        float2 vt2 = *(const float2*)&Vt[t * H_ + 2 * lane];
        l0 = l0 * sc + px;
        a0x = a0x * sc + px * (v2.x + vt2.x);
        a0y = a0y * sc + px * (v2.y + vt2.y);
        m0 = nm;
    }

    float outx, outy;
    if (end == beg) {
        outx = 0.f; outy = 0.f;
    } else {
        float nm = fmaxf(m0, m1);
        float s0 = __expf(m0 - nm), s1 = __expf(m1 - nm);  // exp(-inf)=0 ok
        float L = l0 * s0 + l1 * s1;
        float invL = 1.f / L;
        outx = (a0x * s0 + a1x * s1) * invL;
        outy = (a0y * s0 + a1y * s1) * invL;
    }
    float2 o = make_float2(outx, outy);
    *(float2*)&agg[bn * H_ + 2 * lane] = o;
}

// ---------------------------------------------------------------------------
// MLP + residual + LayerNorm via MFMA.  One wave per 16-node M-tile.
// GEMM1: [h|agg|t](16x384) @ W1 -> silu -> LDS(bf16, wave-private) ->
// GEMM2 @ W2 -> +hidden -> LayerNorm.  No barriers (wave-private LDS).
// ---------------------------------------------------------------------------
__global__ __launch_bounds__(256)
void mlp_mfma_kernel(const float* __restrict__ hidden, const float* __restrict__ agg,
                     const float* __restrict__ time_emb,
                     const unsigned short* __restrict__ W1s,
                     const unsigned short* __restrict__ W2s,
                     const float* __restrict__ b1, const float* __restrict__ b2,
                     const float* __restrict__ gamma, const float* __restrict__ beta,
                     float* __restrict__ out)
{
    __shared__ __align__(16) unsigned short h1s[4][16][136];
    const int wv = threadIdx.x >> 6, lane = threadIdx.x & 63;
    const int tile = blockIdx.x * 4 + wv;
    if (tile >= (B_ * N_) / 16) return;
    const int nbase = tile * 16;
    const int m = lane & 15, q = lane >> 4;
    const int koff = q * 8;

    bf16x8 a[12];
    const float* srcs[3] = { hidden, agg, time_emb };
#pragma unroll
    for (int s3 = 0; s3 < 3; ++s3) {
        const float* p = srcs[s3] + (nbase + m) * H_ + koff;
#pragma unroll
        for (int kc = 0; kc < 4; ++kc) {
            float4 x0 = *(const float4*)(p + kc * 32);
            float4 x1 = *(const float4*)(p + kc * 32 + 4);
            bf16x8 f;
            f[0]=(__bf16)x0.x; f[1]=(__bf16)x0.y; f[2]=(__bf16)x0.z; f[3]=(__bf16)x0.w;
            f[4]=(__bf16)x1.x; f[5]=(__bf16)x1.y; f[6]=(__bf16)x1.z; f[7]=(__bf16)x1.w;
            a[s3 * 4 + kc] = f;
        }
    }

    f32x4 acc[8];
#pragma unroll
    for (int nt = 0; nt < 8; ++nt) acc[nt] = (f32x4)0.f;
#pragma unroll
    for (int kc = 0; kc < 12; ++kc) {
#pragma unroll
        for (int nt = 0; nt < 8; ++nt) {
            bf16x8 bf = ldfrag(W1s, kc, nt, lane);
            acc[nt] = __builtin_amdgcn_mfma_f32_16x16x32_bf16(a[kc], bf, acc[nt], 0, 0, 0);
        }
    }

    // silu -> wave-private LDS (bf16), D-layout -> A-layout transform
#pragma unroll
    for (int nt = 0; nt < 8; ++nt) {
        int col = nt * 16 + m;
        float bb = b1[col];
#pragma unroll
        for (int r = 0; r < 4; ++r) {
            float v = acc[nt][r] + bb;
            float h = v / (1.f + __expf(-v));
            h1s[wv][q * 4 + r][col] = bf16b(h);
        }
    }

    f32x4 acc2[8];
#pragma unroll
    for (int nt = 0; nt < 8; ++nt) acc2[nt] = (f32x4)0.f;
#pragma unroll
    for (int kc = 0; kc < 4; ++kc) {
        short8 s8 = *(const short8*)&h1s[wv][m][kc * 32 + koff];
        bf16x8 a2 = __builtin_bit_cast(bf16x8, s8);
#pragma unroll
        for (int nt = 0; nt < 8; ++nt) {
            bf16x8 bf = ldfrag(W2s, kc, nt, lane);
            acc2[nt] = __builtin_amdgcn_mfma_f32_16x16x32_bf16(a2, bf, acc2[nt], 0, 0, 0);
        }
    }

    // residual + LayerNorm
    float x[8][4];
#pragma unroll
    for (int nt = 0; nt < 8; ++nt) {
        int col = nt * 16 + m;
        float bb = b2[col];
#pragma unroll
        for (int r = 0; r < 4; ++r) {
            int node = nbase + q * 4 + r;
            x[nt][r] = hidden[node * H_ + col] + acc2[nt][r] + bb;
        }
    }
#pragma unroll
    for (int r = 0; r < 4; ++r) {
        float s = 0.f, ss = 0.f;
#pragma unroll
        for (int nt = 0; nt < 8; ++nt) { s += x[nt][r]; ss += x[nt][r] * x[nt][r]; }
#pragma unroll
        for (int off = 1; off < 16; off <<= 1) {
            s  += __shfl_xor(s, off);
            ss += __shfl_xor(ss, off);
        }
        float mu  = s * (1.f / H_);
        float var = ss * (1.f / H_) - mu * mu;
        float rs  = rsqrtf(var + EPS_);
        int node = nbase + q * 4 + r;
#pragma unroll
        for (int nt = 0; nt < 8; ++nt) {
            int col = nt * 16 + m;
            out[node * H_ + col] = (x[nt][r] - mu) * rs * gamma[col] + beta[col];
        }
    }
}

// ---------------------------------------------------------------------------
extern "C" void kernel_launch(void* const* d_in, const int* in_sizes, int n_in,
                              void* d_out, int out_size, void* d_ws, size_t ws_size,
                              hipStream_t stream)
{
    const float* hidden   = (const float*)d_in[0];
    const float* time_emb = (const float*)d_in[1];
    const int*   eidx     = (const int*)d_in[2];
    const int*   etype    = (const int*)d_in[3];
    const float* edge_emb = (const float*)d_in[4];
    const float* Wq = (const float*)d_in[5];
    const float* bq = (const float*)d_in[6];
    const float* Wk = (const float*)d_in[7];
    const float* bk = (const float*)d_in[8];
    const float* Wv = (const float*)d_in[9];
    const float* bv = (const float*)d_in[10];
    const float* We = (const float*)d_in[11];
    const float* be = (const float*)d_in[12];
    const float* W1 = (const float*)d_in[13];
    const float* b1 = (const float*)d_in[14];
    const float* W2 = (const float*)d_in[15];
    const float* b2 = (const float*)d_in[16];
    const float* gamma = (const float*)d_in[17];
    const float* beta  = (const float*)d_in[18];
    float* out = (float*)d_out;

    constexpr int BNH = B_ * N_ * H_;
    float* Q   = (float*)d_ws;
    float* K   = Q + BNH;
    float* V   = K + BNH;
    float* agg = V + BNH;
    float* Kt  = agg + BNH;
    float* Vt  = Kt + ET_ * H_;
    float* ebt = Vt + ET_ * H_;
    int* hist   = (int*)(ebt + ET_);
    int* offs   = hist + N_;
    int* cursor = offs + (N_ + 1);
    int* sorted = cursor + N_;
    uintptr_t wp = (uintptr_t)(sorted + E_);
    wp = (wp + 15) & ~(uintptr_t)15;
    unsigned short* W1s = (unsigned short*)wp;
    unsigned short* W2s = W1s + 384 * 128;
    unsigned short* Wqs = W2s + 128 * 128;
    unsigned short* Wks = Wqs + 128 * 128;
    unsigned short* Wvs = Wks + 128 * 128;

    const int* esrc = eidx;
    const int* etgt = eidx + E_;

    hipMemsetAsync(hist, 0, N_ * sizeof(int), stream);

    prep_w_kernel<<<28, 512, 0, stream>>>(W1, W2, Wq, Wk, Wv, W1s, W2s, Wqs, Wks, Wvs);
    qkv_mfma_kernel<<<313, 256, 0, stream>>>(hidden, time_emb, Wqs, Wks, Wvs, bq, Q, K, V);
    edgetab_kernel<<<1, 128, 0, stream>>>(edge_emb, Wk, bk, Wv, bv, We, be, Kt, Vt, ebt);
    hist_kernel<<<(E_ + 255) / 256, 256, 0, stream>>>(etgt, hist);
    scan_kernel<<<1, 1024, 0, stream>>>(hist, offs, cursor);
    scatter_kernel<<<(E_ + 255) / 256, 256, 0, stream>>>(esrc, etgt, etype, cursor, sorted);
    attn_kernel<<<(B_ * N_) / 4, 256, 0, stream>>>(Q, K, V, Kt, Vt, ebt, offs, sorted, agg);
    mlp_mfma_kernel<<<313, 256, 0, stream>>>(hidden, agg, time_emb, W1s, W2s, b1, b2, gamma, beta, out);
}

// Round 4
// 212.627 us; speedup vs baseline: 2.0168x; 1.2080x over previous
//
#include <hip/hip_runtime.h>
#include <math.h>

constexpr int B_  = 2;
constexpr int N_  = 10000;
constexpr int E_  = 160000;
constexpr int H_  = 128;
constexpr int ET_ = 8;
constexpr float EPS_ = 1e-5f;
constexpr float RSQH = 0.08838834764831845f; // 1/sqrt(128)

typedef __bf16 bf16x8 __attribute__((ext_vector_type(8)));
typedef short  short8 __attribute__((ext_vector_type(8)));
typedef float  f32x4  __attribute__((ext_vector_type(4)));
typedef unsigned short u16;

__device__ inline u16 bf16b(float f) {
    return __builtin_bit_cast(u16, (__bf16)f);
}

// ---------------------------------------------------------------------------
// Weight prep: f32 [K x 128] -> bf16 B-fragment-swizzled layout.
// ---------------------------------------------------------------------------
__global__ __launch_bounds__(512)
void prep_w_kernel(const float* __restrict__ W1, const float* __restrict__ W2,
                   const float* __restrict__ Wq, const float* __restrict__ Wk,
                   const float* __restrict__ Wv,
                   u16* __restrict__ W1s, u16* __restrict__ W2s,
                   u16* __restrict__ Wqs, u16* __restrict__ Wks,
                   u16* __restrict__ Wvs)
{
    int bid = blockIdx.x;
    const float* src; u16* dst; int kc;
    if (bid < 12)      { src = W1; dst = W1s; kc = bid; }
    else if (bid < 16) { src = W2; dst = W2s; kc = bid - 12; }
    else if (bid < 20) { src = Wq; dst = Wqs; kc = bid - 16; }
    else if (bid < 24) { src = Wk; dst = Wks; kc = bid - 20; }
    else               { src = Wv; dst = Wvs; kc = bid - 24; }
    int nt = threadIdx.x >> 6, lane = threadIdx.x & 63;
    int q = lane >> 4, c = lane & 15;
    int kbase = kc * 32 + q * 8;
    int col = nt * 16 + c;
    u16* out = dst + ((kc * 8 + nt) * 64 + lane) * 8;
#pragma unroll
    for (int j = 0; j < 8; ++j)
        out[j] = bf16b(src[(kbase + j) * H_ + col]);
}

__device__ inline bf16x8 ldfrag(const u16* __restrict__ W, int kc, int nt, int lane) {
    short8 s = *(const short8*)(W + ((kc * 8 + nt) * 64 + lane) * 8);
    return __builtin_bit_cast(bf16x8, s);
}

// ---------------------------------------------------------------------------
// Q/K/V via MFMA -> bf16 outputs.
// ---------------------------------------------------------------------------
__global__ __launch_bounds__(256)
void qkv_mfma_kernel(const float* __restrict__ hidden, const float* __restrict__ time_emb,
                     const u16* __restrict__ Wqs, const u16* __restrict__ Wks,
                     const u16* __restrict__ Wvs, const float* __restrict__ bq,
                     u16* __restrict__ Q, u16* __restrict__ K, u16* __restrict__ V)
{
    const int wv = threadIdx.x >> 6, lane = threadIdx.x & 63;
    const int tile = blockIdx.x * 4 + wv;
    if (tile >= (B_ * N_) / 16) return;
    const int nbase = tile * 16;
    const int m = lane & 15, q = lane >> 4;
    const int koff = q * 8;

    bf16x8 aq[4], av[4];
    const float* hp = hidden   + (nbase + m) * H_ + koff;
    const float* tp = time_emb + (nbase + m) * H_ + koff;
#pragma unroll
    for (int kc = 0; kc < 4; ++kc) {
        float4 h0 = *(const float4*)(hp + kc * 32);
        float4 h1 = *(const float4*)(hp + kc * 32 + 4);
        float4 t0 = *(const float4*)(tp + kc * 32);
        float4 t1 = *(const float4*)(tp + kc * 32 + 4);
        bf16x8 fv, fq;
        fv[0]=(__bf16)h0.x; fv[1]=(__bf16)h0.y; fv[2]=(__bf16)h0.z; fv[3]=(__bf16)h0.w;
        fv[4]=(__bf16)h1.x; fv[5]=(__bf16)h1.y; fv[6]=(__bf16)h1.z; fv[7]=(__bf16)h1.w;
        fq[0]=(__bf16)(h0.x+t0.x); fq[1]=(__bf16)(h0.y+t0.y);
        fq[2]=(__bf16)(h0.z+t0.z); fq[3]=(__bf16)(h0.w+t0.w);
        fq[4]=(__bf16)(h1.x+t1.x); fq[5]=(__bf16)(h1.y+t1.y);
        fq[6]=(__bf16)(h1.z+t1.z); fq[7]=(__bf16)(h1.w+t1.w);
        av[kc] = fv; aq[kc] = fq;
    }

    f32x4 accq[8], acck[8], accv[8];
#pragma unroll
    for (int nt = 0; nt < 8; ++nt) { accq[nt] = (f32x4)0.f; acck[nt] = (f32x4)0.f; accv[nt] = (f32x4)0.f; }

#pragma unroll
    for (int kc = 0; kc < 4; ++kc) {
#pragma unroll
        for (int nt = 0; nt < 8; ++nt) {
            bf16x8 bfq = ldfrag(Wqs, kc, nt, lane);
            bf16x8 bfk = ldfrag(Wks, kc, nt, lane);
            bf16x8 bfv = ldfrag(Wvs, kc, nt, lane);
            accq[nt] = __builtin_amdgcn_mfma_f32_16x16x32_bf16(aq[kc], bfq, accq[nt], 0, 0, 0);
            acck[nt] = __builtin_amdgcn_mfma_f32_16x16x32_bf16(aq[kc], bfk, acck[nt], 0, 0, 0);
            accv[nt] = __builtin_amdgcn_mfma_f32_16x16x32_bf16(av[kc], bfv, accv[nt], 0, 0, 0);
        }
    }

#pragma unroll
    for (int nt = 0; nt < 8; ++nt) {
        int col = nt * 16 + m;
        float bqc = bq[col];
#pragma unroll
        for (int r = 0; r < 4; ++r) {
            int node = nbase + q * 4 + r;
            Q[node * H_ + col] = bf16b(accq[nt][r] + bqc);
            K[node * H_ + col] = bf16b(acck[nt][r]);
            V[node * H_ + col] = bf16b(accv[nt][r]);
        }
    }
}

// ---------------------------------------------------------------------------
// Per-edge-type tables, one block per type.
// ---------------------------------------------------------------------------
__global__ __launch_bounds__(128)
void edgetab_kernel(const float* __restrict__ edge_emb,
                    const float* __restrict__ Wk, const float* __restrict__ bk,
                    const float* __restrict__ Wv, const float* __restrict__ bv,
                    const float* __restrict__ We, const float* __restrict__ be,
                    float* __restrict__ Kt, float* __restrict__ Vt, float* __restrict__ eb)
{
    const int t = blockIdx.x, j = threadIdx.x;
    const float* ep = edge_emb + t * H_;
    float ak = bk[j], av = bv[j];
    for (int d = 0; d < H_; d += 4) {
        float e0 = ep[d], e1 = ep[d+1], e2 = ep[d+2], e3 = ep[d+3];
        ak += e0*Wk[(d+0)*H_+j] + e1*Wk[(d+1)*H_+j] + e2*Wk[(d+2)*H_+j] + e3*Wk[(d+3)*H_+j];
        av += e0*Wv[(d+0)*H_+j] + e1*Wv[(d+1)*H_+j] + e2*Wv[(d+2)*H_+j] + e3*Wv[(d+3)*H_+j];
    }
    Kt[t*H_ + j] = ak;
    Vt[t*H_ + j] = av;

    __shared__ float red[2];
    float pe = ep[j] * We[j];
#pragma unroll
    for (int off = 32; off; off >>= 1) pe += __shfl_xor(pe, off);
    if ((j & 63) == 0) red[j >> 6] = pe;
    __syncthreads();
    if (j == 0) eb[t] = red[0] + red[1] + be[0];
}

// ---------------------------------------------------------------------------
// CSR build: histogram, wave-shuffle scan, scatter.
// ---------------------------------------------------------------------------
__global__ void hist_kernel(const int* __restrict__ tgt, int* __restrict__ hist)
{
    int e = blockIdx.x * blockDim.x + threadIdx.x;
    if (e < E_) atomicAdd(&hist[tgt[e]], 1);
}

__global__ __launch_bounds__(1024)
void scan_kernel(const int* __restrict__ hist, int* __restrict__ offs, int* __restrict__ cursor)
{
    __shared__ int wpart[16];
    __shared__ int wexcl[16];
    __shared__ int carry_s;
    const int tid = threadIdx.x, wave = tid >> 6, lane = tid & 63;
    if (tid == 0) carry_s = 0;
    __syncthreads();
    for (int base = 0; base < N_; base += 1024) {
        int idx = base + tid;
        int v = (idx < N_) ? hist[idx] : 0;
        int s = v;
#pragma unroll
        for (int off = 1; off < 64; off <<= 1) {
            int t = __shfl_up(s, off);
            if (lane >= off) s += t;
        }
        if (lane == 63) wpart[wave] = s;
        __syncthreads();
        if (tid == 0) {
            int c = carry_s;
            for (int w = 0; w < 16; ++w) { int p = wpart[w]; wexcl[w] = c; c += p; }
            carry_s = c;
        }
        __syncthreads();
        if (idx < N_) {
            int excl = wexcl[wave] + s - v;
            offs[idx] = excl;
            cursor[idx] = excl;
        }
        __syncthreads();
    }
    if (threadIdx.x == 0) offs[N_] = carry_s;
}

__global__ void scatter_kernel(const int* __restrict__ src, const int* __restrict__ tgt,
                               const int* __restrict__ type, int* __restrict__ cursor,
                               int* __restrict__ sorted)
{
    int e = blockIdx.x * blockDim.x + threadIdx.x;
    if (e < E_) {
        int t = tgt[e];
        int pos = atomicAdd(&cursor[t], 1);
        sorted[pos] = src[e] | (type[e] << 16);
    }
}

// ---------------------------------------------------------------------------
// Attention: one wave per (b,node).  16-lane groups each own one edge per
// iteration (4 edges in flight per wave); lane holds 8 channels (bf16x8).
// Two-pass per 64-edge chunk: pass1 logits->LDS + max (no rescale chain),
// pass2 independent exps + weighted V accumulate.  Kt folded into per-type
// bias; Vt staged in LDS bf16.
// ---------------------------------------------------------------------------
__global__ __launch_bounds__(256)
void attn_kernel(const u16* __restrict__ Qb, const u16* __restrict__ Kb,
                 const u16* __restrict__ Vb,
                 const float* __restrict__ Kt, const float* __restrict__ Vt,
                 const float* __restrict__ eb,
                 const int* __restrict__ offs, const int* __restrict__ sorted,
                 u16* __restrict__ aggb)
{
    __shared__ float logit_s[4][64];
    __shared__ float bias_s[4][8];
    __shared__ __align__(16) u16 vt_s[8][128];

    const int tid = threadIdx.x;
    const int wv = tid >> 6, lane = tid & 63;
    const int g = lane >> 4, lam = lane & 15;

    // stage Vt (bf16) once per block
    for (int idx = tid; idx < ET_ * H_; idx += 256)
        vt_s[idx >> 7][idx & 127] = bf16b(Vt[idx]);
    __syncthreads();

    // batch-parity mapping: even blocks -> batch 0, odd -> batch 1 (XCD L2 locality)
    const int b = blockIdx.x & 1;
    const int n = (blockIdx.x >> 1) * 4 + wv;
    const int bn = b * N_ + n;
    const int beg = offs[n], end = offs[n + 1];
    const int bbase = b * N_;

    // Q slice: 8 channels per lane (same across groups)
    float q[8];
    {
        short8 s8 = *(const short8*)(Qb + (size_t)bn * H_ + lam * 8);
        bf16x8 qa = __builtin_bit_cast(bf16x8, s8);
#pragma unroll
        for (int j = 0; j < 8; ++j) q[j] = (float)qa[j];
    }

    // per-type logit bias: group g computes types 2g, 2g+1
    {
        const float* k0p = Kt + (2 * g) * H_ + lam * 8;
        const float* k1p = Kt + (2 * g + 1) * H_ + lam * 8;
        float p0 = 0.f, p1 = 0.f;
#pragma unroll
        for (int j = 0; j < 8; ++j) { p0 += q[j] * k0p[j]; p1 += q[j] * k1p[j]; }
#pragma unroll
        for (int msk = 1; msk < 16; msk <<= 1) {
            p0 += __shfl_xor(p0, msk);
            p1 += __shfl_xor(p1, msk);
        }
        if (lam == 0) {
            bias_s[wv][2 * g]     = p0 * RSQH + eb[2 * g];
            bias_s[wv][2 * g + 1] = p1 * RSQH + eb[2 * g + 1];
        }
    }

    float m_run = -INFINITY, l = 0.f;
    float acc[8];
#pragma unroll
    for (int j = 0; j < 8; ++j) acc[j] = 0.f;

    for (int cb = beg; cb < end; cb += 64) {
        const int cnt = min(64, end - cb);
        // ---- pass 1: logits + chunk max ----
        float gmax = -INFINITY;
        for (int c = g; c < cnt; c += 4) {
            int pk = sorted[cb + c];
            int s = pk & 0xFFFF, t = pk >> 16;
            short8 k8 = *(const short8*)(Kb + (size_t)(bbase + s) * H_ + lam * 8);
            bf16x8 ka = __builtin_bit_cast(bf16x8, k8);
            float p = 0.f;
#pragma unroll
            for (int j = 0; j < 8; ++j) p += q[j] * (float)ka[j];
#pragma unroll
            for (int msk = 1; msk < 16; msk <<= 1) p += __shfl_xor(p, msk);
            float lg = p * RSQH + bias_s[wv][t];
            if (lam == 0) logit_s[wv][c] = lg;
            gmax = fmaxf(gmax, lg);
        }
        gmax = fmaxf(gmax, __shfl_xor(gmax, 16));
        gmax = fmaxf(gmax, __shfl_xor(gmax, 32));
        float Mn = fmaxf(m_run, gmax);
        float rs = __expf(m_run - Mn);   // first chunk: exp(-inf)=0
        l *= rs;
#pragma unroll
        for (int j = 0; j < 8; ++j) acc[j] *= rs;
        m_run = Mn;
        // ---- pass 2: weights + V accumulate ----
        for (int c = g; c < cnt; c += 4) {
            int pk = sorted[cb + c];
            int s = pk & 0xFFFF, t = pk >> 16;
            float w = __expf(logit_s[wv][c] - Mn);
            l += w;
            short8 v8  = *(const short8*)(Vb + (size_t)(bbase + s) * H_ + lam * 8);
            short8 vt8 = *(const short8*)(&vt_s[t][lam * 8]);
            bf16x8 va  = __builtin_bit_cast(bf16x8, v8);
            bf16x8 vta = __builtin_bit_cast(bf16x8, vt8);
#pragma unroll
            for (int j = 0; j < 8; ++j)
                acc[j] += w * ((float)va[j] + (float)vta[j]);
        }
    }

    // merge the 4 groups (same channel slice lives at lane lam in each group)
#pragma unroll
    for (int j = 0; j < 8; ++j) {
        acc[j] += __shfl_xor(acc[j], 16);
        acc[j] += __shfl_xor(acc[j], 32);
    }
    l += __shfl_xor(l, 16);
    l += __shfl_xor(l, 32);

    if (g == 0) {
        float invL = (end > beg) ? 1.f / l : 0.f;
        bf16x8 o;
#pragma unroll
        for (int j = 0; j < 8; ++j) o[j] = (__bf16)(acc[j] * invL);
        *(short8*)(aggb + (size_t)bn * H_ + lam * 8) = __builtin_bit_cast(short8, o);
    }
}

// ---------------------------------------------------------------------------
// MLP + residual + LayerNorm via MFMA (agg input now bf16 = direct A-frag).
// ---------------------------------------------------------------------------
__global__ __launch_bounds__(256)
void mlp_mfma_kernel(const float* __restrict__ hidden, const u16* __restrict__ aggb,
                     const float* __restrict__ time_emb,
                     const u16* __restrict__ W1s, const u16* __restrict__ W2s,
                     const float* __restrict__ b1, const float* __restrict__ b2,
                     const float* __restrict__ gamma, const float* __restrict__ beta,
                     float* __restrict__ out)
{
    __shared__ __align__(16) u16 h1s[4][16][136];
    const int wv = threadIdx.x >> 6, lane = threadIdx.x & 63;
    const int tile = blockIdx.x * 4 + wv;
    if (tile >= (B_ * N_) / 16) return;
    const int nbase = tile * 16;
    const int m = lane & 15, q = lane >> 4;
    const int koff = q * 8;

    bf16x8 a[12];
    const float* hp = hidden   + (nbase + m) * H_ + koff;
    const float* tp = time_emb + (nbase + m) * H_ + koff;
    const u16*   ap = aggb + (size_t)(nbase + m) * H_ + koff;
#pragma unroll
    for (int kc = 0; kc < 4; ++kc) {
        float4 h0 = *(const float4*)(hp + kc * 32);
        float4 h1 = *(const float4*)(hp + kc * 32 + 4);
        float4 t0 = *(const float4*)(tp + kc * 32);
        float4 t1 = *(const float4*)(tp + kc * 32 + 4);
        bf16x8 fh, ft;
        fh[0]=(__bf16)h0.x; fh[1]=(__bf16)h0.y; fh[2]=(__bf16)h0.z; fh[3]=(__bf16)h0.w;
        fh[4]=(__bf16)h1.x; fh[5]=(__bf16)h1.y; fh[6]=(__bf16)h1.z; fh[7]=(__bf16)h1.w;
        ft[0]=(__bf16)t0.x; ft[1]=(__bf16)t0.y; ft[2]=(__bf16)t0.z; ft[3]=(__bf16)t0.w;
        ft[4]=(__bf16)t1.x; ft[5]=(__bf16)t1.y; ft[6]=(__bf16)t1.z; ft[7]=(__bf16)t1.w;
        a[0 * 4 + kc] = fh;
        a[2 * 4 + kc] = ft;
        short8 s8 = *(const short8*)(ap + kc * 32);
        a[1 * 4 + kc] = __builtin_bit_cast(bf16x8, s8);
    }

    f32x4 acc[8];
#pragma unroll
    for (int nt = 0; nt < 8; ++nt) acc[nt] = (f32x4)0.f;
#pragma unroll
    for (int kc = 0; kc < 12; ++kc) {
#pragma unroll
        for (int nt = 0; nt < 8; ++nt) {
            bf16x8 bf = ldfrag(W1s, kc, nt, lane);
            acc[nt] = __builtin_amdgcn_mfma_f32_16x16x32_bf16(a[kc], bf, acc[nt], 0, 0, 0);
        }
    }

    // silu -> wave-private LDS (bf16), D-layout -> A-layout
#pragma unroll
    for (int nt = 0; nt < 8; ++nt) {
        int col = nt * 16 + m;
        float bb = b1[col];
#pragma unroll
        for (int r = 0; r < 4; ++r) {
            float v = acc[nt][r] + bb;
            float h = v / (1.f + __expf(-v));
            h1s[wv][q * 4 + r][col] = bf16b(h);
        }
    }

    f32x4 acc2[8];
#pragma unroll
    for (int nt = 0; nt < 8; ++nt) acc2[nt] = (f32x4)0.f;
#pragma unroll
    for (int kc = 0; kc < 4; ++kc) {
        short8 s8 = *(const short8*)&h1s[wv][m][kc * 32 + koff];
        bf16x8 a2 = __builtin_bit_cast(bf16x8, s8);
#pragma unroll
        for (int nt = 0; nt < 8; ++nt) {
            bf16x8 bf = ldfrag(W2s, kc, nt, lane);
            acc2[nt] = __builtin_amdgcn_mfma_f32_16x16x32_bf16(a2, bf, acc2[nt], 0, 0, 0);
        }
    }

    // residual + LayerNorm
    float x[8][4];
#pragma unroll
    for (int nt = 0; nt < 8; ++nt) {
        int col = nt * 16 + m;
        float bb = b2[col];
#pragma unroll
        for (int r = 0; r < 4; ++r) {
            int node = nbase + q * 4 + r;
            x[nt][r] = hidden[node * H_ + col] + acc2[nt][r] + bb;
        }
    }
#pragma unroll
    for (int r = 0; r < 4; ++r) {
        float s = 0.f, ss = 0.f;
#pragma unroll
        for (int nt = 0; nt < 8; ++nt) { s += x[nt][r]; ss += x[nt][r] * x[nt][r]; }
#pragma unroll
        for (int off = 1; off < 16; off <<= 1) {
            s  += __shfl_xor(s, off);
            ss += __shfl_xor(ss, off);
        }
        float mu  = s * (1.f / H_);
        float var = ss * (1.f / H_) - mu * mu;
        float rs  = rsqrtf(var + EPS_);
        int node = nbase + q * 4 + r;
#pragma unroll
        for (int nt = 0; nt < 8; ++nt) {
            int col = nt * 16 + m;
            out[node * H_ + col] = (x[nt][r] - mu) * rs * gamma[col] + beta[col];
        }
    }
}

// ---------------------------------------------------------------------------
extern "C" void kernel_launch(void* const* d_in, const int* in_sizes, int n_in,
                              void* d_out, int out_size, void* d_ws, size_t ws_size,
                              hipStream_t stream)
{
    const float* hidden   = (const float*)d_in[0];
    const float* time_emb = (const float*)d_in[1];
    const int*   eidx     = (const int*)d_in[2];
    const int*   etype    = (const int*)d_in[3];
    const float* edge_emb = (const float*)d_in[4];
    const float* Wq = (const float*)d_in[5];
    const float* bq = (const float*)d_in[6];
    const float* Wk = (const float*)d_in[7];
    const float* bk = (const float*)d_in[8];
    const float* Wv = (const float*)d_in[9];
    const float* bv = (const float*)d_in[10];
    const float* We = (const float*)d_in[11];
    const float* be = (const float*)d_in[12];
    const float* W1 = (const float*)d_in[13];
    const float* b1 = (const float*)d_in[14];
    const float* W2 = (const float*)d_in[15];
    const float* b2 = (const float*)d_in[16];
    const float* gamma = (const float*)d_in[17];
    const float* beta  = (const float*)d_in[18];
    float* out = (float*)d_out;

    constexpr int BNH = B_ * N_ * H_;
    u16* Qb   = (u16*)d_ws;
    u16* Kb   = Qb + BNH;
    u16* Vb   = Kb + BNH;
    u16* aggb = Vb + BNH;
    float* Kt  = (float*)(aggb + BNH);          // byte offset 4*BNH*2 = 16-aligned
    float* Vt  = Kt + ET_ * H_;
    float* ebt = Vt + ET_ * H_;
    int* hist   = (int*)(ebt + ET_);
    int* offs   = hist + N_;
    int* cursor = offs + (N_ + 1);
    int* sorted = cursor + N_;
    uintptr_t wp = (uintptr_t)(sorted + E_);
    wp = (wp + 15) & ~(uintptr_t)15;
    u16* W1s = (u16*)wp;
    u16* W2s = W1s + 384 * 128;
    u16* Wqs = W2s + 128 * 128;
    u16* Wks = Wqs + 128 * 128;
    u16* Wvs = Wks + 128 * 128;

    const int* esrc = eidx;
    const int* etgt = eidx + E_;

    hipMemsetAsync(hist, 0, N_ * sizeof(int), stream);

    prep_w_kernel<<<28, 512, 0, stream>>>(W1, W2, Wq, Wk, Wv, W1s, W2s, Wqs, Wks, Wvs);
    qkv_mfma_kernel<<<313, 256, 0, stream>>>(hidden, time_emb, Wqs, Wks, Wvs, bq, Qb, Kb, Vb);
    edgetab_kernel<<<ET_, 128, 0, stream>>>(edge_emb, Wk, bk, Wv, bv, We, be, Kt, Vt, ebt);
    hist_kernel<<<(E_ + 255) / 256, 256, 0, stream>>>(etgt, hist);
    scan_kernel<<<1, 1024, 0, stream>>>(hist, offs, cursor);
    scatter_kernel<<<(E_ + 255) / 256, 256, 0, stream>>>(esrc, etgt, etype, cursor, sorted);
    attn_kernel<<<(B_ * N_) / 4, 256, 0, stream>>>(Qb, Kb, Vb, Kt, Vt, ebt, offs, sorted, aggb);
    mlp_mfma_kernel<<<313, 256, 0, stream>>>(hidden, aggb, time_emb, W1s, W2s, b1, b2, gamma, beta, out);
}

// Round 6
// 195.438 us; speedup vs baseline: 2.1942x; 1.0880x over previous
//
#include <hip/hip_runtime.h>
#include <math.h>

constexpr int B_  = 2;
constexpr int N_  = 10000;
constexpr int E_  = 160000;
constexpr int H_  = 128;
constexpr int ET_ = 8;
constexpr float EPS_ = 1e-5f;
constexpr float RSQH = 0.08838834764831845f; // 1/sqrt(128)

typedef __bf16 bf16x8 __attribute__((ext_vector_type(8)));
typedef short  short8 __attribute__((ext_vector_type(8)));
typedef float  f32x4  __attribute__((ext_vector_type(4)));
typedef unsigned short u16;

__device__ inline u16 bf16b(float f) {
    return __builtin_bit_cast(u16, (__bf16)f);
}

__device__ inline bf16x8 ldfrag(const u16* __restrict__ W, int kc, int nt, int lane) {
    short8 s = *(const short8*)(W + ((kc * 8 + nt) * 64 + lane) * 8);
    return __builtin_bit_cast(bf16x8, s);
}

// ---------------------------------------------------------------------------
// Fused setup: blocks [0,56) weight-prep, [56,64) edge-type tables,
// [64,689) tgt histogram.
// ---------------------------------------------------------------------------
__global__ __launch_bounds__(256)
void setup_kernel(const float* __restrict__ W1, const float* __restrict__ W2,
                  const float* __restrict__ Wq, const float* __restrict__ Wk,
                  const float* __restrict__ Wv,
                  u16* __restrict__ W1s, u16* __restrict__ W2s,
                  u16* __restrict__ Wqs, u16* __restrict__ Wks, u16* __restrict__ Wvs,
                  const float* __restrict__ edge_emb,
                  const float* __restrict__ bk, const float* __restrict__ bv,
                  const float* __restrict__ We, const float* __restrict__ be,
                  float* __restrict__ Kt, float* __restrict__ Vt, float* __restrict__ eb,
                  const int* __restrict__ tgt, int* __restrict__ hist)
{
    const int bid = blockIdx.x, tid = threadIdx.x;
    if (bid < 56) {
        // weight prep: f32 [Kx128] -> bf16 B-frag swizzle
        int unit = bid >> 1, half = bid & 1;
        const float* src; u16* dst; int kc;
        if (unit < 12)      { src = W1; dst = W1s; kc = unit; }
        else if (unit < 16) { src = W2; dst = W2s; kc = unit - 12; }
        else if (unit < 20) { src = Wq; dst = Wqs; kc = unit - 16; }
        else if (unit < 24) { src = Wk; dst = Wks; kc = unit - 20; }
        else                { src = Wv; dst = Wvs; kc = unit - 24; }
        int nt = half * 4 + (tid >> 6), lane = tid & 63;
        int q = lane >> 4, c = lane & 15;
        int kbase = kc * 32 + q * 8;
        int col = nt * 16 + c;
        u16* out = dst + ((kc * 8 + nt) * 64 + lane) * 8;
#pragma unroll
        for (int j = 0; j < 8; ++j)
            out[j] = bf16b(src[(kbase + j) * H_ + col]);
    } else if (bid < 64) {
        // edge-type tables: Kt=e@Wk+bk, Vt=e@Wv+bv, eb=e@We+be
        int t = bid - 56;
        const float* ep = edge_emb + t * H_;
        __shared__ float red[2];
        int j = tid;
        if (j < 128) {
            float ak = bk[j], av = bv[j];
            for (int d = 0; d < H_; d += 4) {
                float e0 = ep[d], e1 = ep[d+1], e2 = ep[d+2], e3 = ep[d+3];
                ak += e0*Wk[(d+0)*H_+j] + e1*Wk[(d+1)*H_+j] + e2*Wk[(d+2)*H_+j] + e3*Wk[(d+3)*H_+j];
                av += e0*Wv[(d+0)*H_+j] + e1*Wv[(d+1)*H_+j] + e2*Wv[(d+2)*H_+j] + e3*Wv[(d+3)*H_+j];
            }
            Kt[t*H_ + j] = ak;
            Vt[t*H_ + j] = av;
            float pe = ep[j] * We[j];
#pragma unroll
            for (int off = 32; off; off >>= 1) pe += __shfl_xor(pe, off);
            if ((j & 63) == 0) red[j >> 6] = pe;
        }
        __syncthreads();
        if (j == 0) eb[t] = red[0] + red[1] + be[0];
    } else {
        int e = (bid - 64) * 256 + tid;
        if (e < E_) atomicAdd(&hist[tgt[e]], 1);
    }
}

// ---------------------------------------------------------------------------
// Single-pass exclusive scan: 1024 threads x 10 elements, 2 barriers.
// ---------------------------------------------------------------------------
__global__ __launch_bounds__(1024)
void scan_kernel(const int* __restrict__ hist, int* __restrict__ offs,
                 int* __restrict__ cursor)
{
    __shared__ int winc[16];
    const int tid = threadIdx.x, wave = tid >> 6, lane = tid & 63;
    int v[10];
    const int idx0 = tid * 10;
    int tot = 0;
#pragma unroll
    for (int i = 0; i < 10; ++i) {
        int idx = idx0 + i;
        v[i] = (idx < N_) ? hist[idx] : 0;
        tot += v[i];
    }
    int s = tot;
#pragma unroll
    for (int off = 1; off < 64; off <<= 1) {
        int t = __shfl_up(s, off);
        if (lane >= off) s += t;
    }
    if (lane == 63) winc[wave] = s;
    __syncthreads();
    if (tid < 16) {
        int si = winc[tid];
#pragma unroll
        for (int off = 1; off < 16; off <<= 1) {
            int t = __shfl_up(si, off);
            if (tid >= off) si += t;
        }
        winc[tid] = si;   // inclusive scan of wave totals
    }
    __syncthreads();
    int wbase = (wave == 0) ? 0 : winc[wave - 1];
    int run = wbase + (s - tot);
#pragma unroll
    for (int i = 0; i < 10; ++i) {
        int idx = idx0 + i;
        if (idx < N_) { offs[idx] = run; cursor[idx] = run; }
        run += v[i];
    }
    if (tid == 0) offs[N_] = winc[15];
}

// ---------------------------------------------------------------------------
// Fused scatter (blocks [0,625)) + Q/K/V MFMA (blocks [625,938)).
// ---------------------------------------------------------------------------
__global__ __launch_bounds__(256)
void scatter_qkv_kernel(const int* __restrict__ src, const int* __restrict__ tgt,
                        const int* __restrict__ type, int* __restrict__ cursor,
                        int* __restrict__ sorted,
                        const float* __restrict__ hidden, const float* __restrict__ time_emb,
                        const u16* __restrict__ Wqs, const u16* __restrict__ Wks,
                        const u16* __restrict__ Wvs, const float* __restrict__ bq,
                        u16* __restrict__ Q, u16* __restrict__ K, u16* __restrict__ V)
{
    if (blockIdx.x < 625) {
        int e = blockIdx.x * 256 + threadIdx.x;
        if (e < E_) {
            int t = tgt[e];
            int pos = atomicAdd(&cursor[t], 1);
            sorted[pos] = src[e] | (type[e] << 16);
        }
        return;
    }
    const int wv = threadIdx.x >> 6, lane = threadIdx.x & 63;
    const int tile = (blockIdx.x - 625) * 4 + wv;
    if (tile >= (B_ * N_) / 16) return;
    const int nbase = tile * 16;
    const int m = lane & 15, q = lane >> 4;
    const int koff = q * 8;

    bf16x8 aq[4], av[4];
    const float* hp = hidden   + (nbase + m) * H_ + koff;
    const float* tp = time_emb + (nbase + m) * H_ + koff;
#pragma unroll
    for (int kc = 0; kc < 4; ++kc) {
        float4 h0 = *(const float4*)(hp + kc * 32);
        float4 h1 = *(const float4*)(hp + kc * 32 + 4);
        float4 t0 = *(const float4*)(tp + kc * 32);
        float4 t1 = *(const float4*)(tp + kc * 32 + 4);
        bf16x8 fv, fq;
        fv[0]=(__bf16)h0.x; fv[1]=(__bf16)h0.y; fv[2]=(__bf16)h0.z; fv[3]=(__bf16)h0.w;
        fv[4]=(__bf16)h1.x; fv[5]=(__bf16)h1.y; fv[6]=(__bf16)h1.z; fv[7]=(__bf16)h1.w;
        fq[0]=(__bf16)(h0.x+t0.x); fq[1]=(__bf16)(h0.y+t0.y);
        fq[2]=(__bf16)(h0.z+t0.z); fq[3]=(__bf16)(h0.w+t0.w);
        fq[4]=(__bf16)(h1.x+t1.x); fq[5]=(__bf16)(h1.y+t1.y);
        fq[6]=(__bf16)(h1.z+t1.z); fq[7]=(__bf16)(h1.w+t1.w);
        av[kc] = fv; aq[kc] = fq;
    }

    f32x4 accq[8], acck[8], accv[8];
#pragma unroll
    for (int nt = 0; nt < 8; ++nt) { accq[nt] = (f32x4)0.f; acck[nt] = (f32x4)0.f; accv[nt] = (f32x4)0.f; }

#pragma unroll
    for (int kc = 0; kc < 4; ++kc) {
#pragma unroll
        for (int nt = 0; nt < 8; ++nt) {
            bf16x8 bfq = ldfrag(Wqs, kc, nt, lane);
            bf16x8 bfk = ldfrag(Wks, kc, nt, lane);
            bf16x8 bfv = ldfrag(Wvs, kc, nt, lane);
            accq[nt] = __builtin_amdgcn_mfma_f32_16x16x32_bf16(aq[kc], bfq, accq[nt], 0, 0, 0);
            acck[nt] = __builtin_amdgcn_mfma_f32_16x16x32_bf16(aq[kc], bfk, acck[nt], 0, 0, 0);
            accv[nt] = __builtin_amdgcn_mfma_f32_16x16x32_bf16(av[kc], bfv, accv[nt], 0, 0, 0);
        }
    }

#pragma unroll
    for (int nt = 0; nt < 8; ++nt) {
        int col = nt * 16 + m;
        float bqc = bq[col];
#pragma unroll
        for (int r = 0; r < 4; ++r) {
            int node = nbase + q * 4 + r;
            Q[node * H_ + col] = bf16b(accq[nt][r] + bqc);
            K[node * H_ + col] = bf16b(acck[nt][r]);
            V[node * H_ + col] = bf16b(accv[nt][r]);
        }
    }
}

// ---------------------------------------------------------------------------
// Attention: one wave per (b,node); 16-lane groups own edges; 2 edges per
// group in flight.  Chunk's packed edge words staged in LDS (written by all
// 64 lanes BEFORE divergence — shfl from divergent lanes is UB, LDS is not).
// ---------------------------------------------------------------------------
__global__ __launch_bounds__(256)
void attn_kernel(const u16* __restrict__ Qb, const u16* __restrict__ Kb,
                 const u16* __restrict__ Vb,
                 const float* __restrict__ Kt, const float* __restrict__ Vt,
                 const float* __restrict__ eb,
                 const int* __restrict__ offs, const int* __restrict__ sorted,
                 u16* __restrict__ aggb)
{
    __shared__ float logit_s[4][64];
    __shared__ float bias_s[4][8];
    __shared__ int   pk_s[4][64];
    __shared__ __align__(16) u16 vt_s[8][128];

    const int tid = threadIdx.x;
    const int wv = tid >> 6, lane = tid & 63;
    const int g = lane >> 4, lam = lane & 15;

    for (int idx = tid; idx < ET_ * H_; idx += 256)
        vt_s[idx >> 7][idx & 127] = bf16b(Vt[idx]);
    __syncthreads();

    const int b = blockIdx.x & 1;                 // batch-parity XCD swizzle
    const int n = (blockIdx.x >> 1) * 4 + wv;
    const int bn = b * N_ + n;
    const int beg = offs[n], end = offs[n + 1];
    const int bbase = b * N_;

    float q[8];
    {
        short8 s8 = *(const short8*)(Qb + (size_t)bn * H_ + lam * 8);
        bf16x8 qa = __builtin_bit_cast(bf16x8, s8);
#pragma unroll
        for (int j = 0; j < 8; ++j) q[j] = (float)qa[j];
    }

    {   // per-type logit bias: group g computes types 2g, 2g+1
        const float* k0p = Kt + (2 * g) * H_ + lam * 8;
        const float* k1p = Kt + (2 * g + 1) * H_ + lam * 8;
        float p0 = 0.f, p1 = 0.f;
#pragma unroll
        for (int j = 0; j < 8; ++j) { p0 += q[j] * k0p[j]; p1 += q[j] * k1p[j]; }
#pragma unroll
        for (int msk = 1; msk < 16; msk <<= 1) {
            p0 += __shfl_xor(p0, msk);
            p1 += __shfl_xor(p1, msk);
        }
        if (lam == 0) {
            bias_s[wv][2 * g]     = p0 * RSQH + eb[2 * g];
            bias_s[wv][2 * g + 1] = p1 * RSQH + eb[2 * g + 1];
        }
    }

    float m_run = -INFINITY, l = 0.f;
    float acc[8];
#pragma unroll
    for (int j = 0; j < 8; ++j) acc[j] = 0.f;

    for (int cb = beg; cb < end; cb += 64) {
        const int cnt = min(64, end - cb);
        pk_s[wv][lane] = (cb + lane < end) ? sorted[cb + lane] : 0;  // all lanes, pre-divergence

        // ---- pass 1: logits + chunk max (2 edges in flight per group) ----
        float gmax = -INFINITY;
        int c = g;
        for (; c + 4 < cnt; c += 8) {
            int pk0 = pk_s[wv][c];
            int pk1 = pk_s[wv][c + 4];
            int s0 = pk0 & 0xFFFF, t0 = pk0 >> 16;
            int s1 = pk1 & 0xFFFF, t1 = pk1 >> 16;
            short8 k80 = *(const short8*)(Kb + (size_t)(bbase + s0) * H_ + lam * 8);
            short8 k81 = *(const short8*)(Kb + (size_t)(bbase + s1) * H_ + lam * 8);
            bf16x8 ka0 = __builtin_bit_cast(bf16x8, k80);
            bf16x8 ka1 = __builtin_bit_cast(bf16x8, k81);
            float p0 = 0.f, p1 = 0.f;
#pragma unroll
            for (int j = 0; j < 8; ++j) {
                p0 += q[j] * (float)ka0[j];
                p1 += q[j] * (float)ka1[j];
            }
#pragma unroll
            for (int msk = 1; msk < 16; msk <<= 1) {
                p0 += __shfl_xor(p0, msk);
                p1 += __shfl_xor(p1, msk);
            }
            float lg0 = p0 * RSQH + bias_s[wv][t0];
            float lg1 = p1 * RSQH + bias_s[wv][t1];
            if (lam == 0) { logit_s[wv][c] = lg0; logit_s[wv][c + 4] = lg1; }
            gmax = fmaxf(gmax, fmaxf(lg0, lg1));
        }
        if (c < cnt) {
            int pk0 = pk_s[wv][c];
            int s0 = pk0 & 0xFFFF, t0 = pk0 >> 16;
            short8 k80 = *(const short8*)(Kb + (size_t)(bbase + s0) * H_ + lam * 8);
            bf16x8 ka0 = __builtin_bit_cast(bf16x8, k80);
            float p0 = 0.f;
#pragma unroll
            for (int j = 0; j < 8; ++j) p0 += q[j] * (float)ka0[j];
#pragma unroll
            for (int msk = 1; msk < 16; msk <<= 1) p0 += __shfl_xor(p0, msk);
            float lg0 = p0 * RSQH + bias_s[wv][t0];
            if (lam == 0) logit_s[wv][c] = lg0;
            gmax = fmaxf(gmax, lg0);
        }
        gmax = fmaxf(gmax, __shfl_xor(gmax, 16));
        gmax = fmaxf(gmax, __shfl_xor(gmax, 32));
        float Mn = fmaxf(m_run, gmax);
        float rs = __expf(m_run - Mn);   // first chunk: exp(-inf)=0
        l *= rs;
#pragma unroll
        for (int j = 0; j < 8; ++j) acc[j] *= rs;
        m_run = Mn;

        // ---- pass 2: weights + V accumulate (2 edges in flight) ----
        c = g;
        for (; c + 4 < cnt; c += 8) {
            int pk0 = pk_s[wv][c];
            int pk1 = pk_s[wv][c + 4];
            int s0 = pk0 & 0xFFFF, t0 = pk0 >> 16;
            int s1 = pk1 & 0xFFFF, t1 = pk1 >> 16;
            short8 v80  = *(const short8*)(Vb + (size_t)(bbase + s0) * H_ + lam * 8);
            short8 v81  = *(const short8*)(Vb + (size_t)(bbase + s1) * H_ + lam * 8);
            short8 vt80 = *(const short8*)(&vt_s[t0][lam * 8]);
            short8 vt81 = *(const short8*)(&vt_s[t1][lam * 8]);
            float w0 = __expf(logit_s[wv][c] - Mn);
            float w1 = __expf(logit_s[wv][c + 4] - Mn);
            l += w0 + w1;
            bf16x8 va0  = __builtin_bit_cast(bf16x8, v80);
            bf16x8 va1  = __builtin_bit_cast(bf16x8, v81);
            bf16x8 vta0 = __builtin_bit_cast(bf16x8, vt80);
            bf16x8 vta1 = __builtin_bit_cast(bf16x8, vt81);
#pragma unroll
            for (int j = 0; j < 8; ++j)
                acc[j] += w0 * ((float)va0[j] + (float)vta0[j])
                        + w1 * ((float)va1[j] + (float)vta1[j]);
        }
        if (c < cnt) {
            int pk0 = pk_s[wv][c];
            int s0 = pk0 & 0xFFFF, t0 = pk0 >> 16;
            short8 v80  = *(const short8*)(Vb + (size_t)(bbase + s0) * H_ + lam * 8);
            short8 vt80 = *(const short8*)(&vt_s[t0][lam * 8]);
            float w0 = __expf(logit_s[wv][c] - Mn);
            l += w0;
            bf16x8 va0  = __builtin_bit_cast(bf16x8, v80);
            bf16x8 vta0 = __builtin_bit_cast(bf16x8, vt80);
#pragma unroll
            for (int j = 0; j < 8; ++j)
                acc[j] += w0 * ((float)va0[j] + (float)vta0[j]);
        }
    }

    // merge the 4 groups (reconverged here)
#pragma unroll
    for (int j = 0; j < 8; ++j) {
        acc[j] += __shfl_xor(acc[j], 16);
        acc[j] += __shfl_xor(acc[j], 32);
    }
    l += __shfl_xor(l, 16);
    l += __shfl_xor(l, 32);

    if (g == 0) {
        float invL = (end > beg) ? 1.f / l : 0.f;
        bf16x8 o;
#pragma unroll
        for (int j = 0; j < 8; ++j) o[j] = (__bf16)(acc[j] * invL);
        *(short8*)(aggb + (size_t)bn * H_ + lam * 8) = __builtin_bit_cast(short8, o);
    }
}

// ---------------------------------------------------------------------------
// MLP + residual + LayerNorm via MFMA.
// ---------------------------------------------------------------------------
__global__ __launch_bounds__(256)
void mlp_mfma_kernel(const float* __restrict__ hidden, const u16* __restrict__ aggb,
                     const float* __restrict__ time_emb,
                     const u16* __restrict__ W1s, const u16* __restrict__ W2s,
                     const float* __restrict__ b1, const float* __restrict__ b2,
                     const float* __restrict__ gamma, const float* __restrict__ beta,
                     float* __restrict__ out)
{
    __shared__ __align__(16) u16 h1s[4][16][136];
    const int wv = threadIdx.x >> 6, lane = threadIdx.x & 63;
    const int tile = blockIdx.x * 4 + wv;
    if (tile >= (B_ * N_) / 16) return;
    const int nbase = tile * 16;
    const int m = lane & 15, q = lane >> 4;
    const int koff = q * 8;

    bf16x8 a[12];
    const float* hp = hidden   + (nbase + m) * H_ + koff;
    const float* tp = time_emb + (nbase + m) * H_ + koff;
    const u16*   ap = aggb + (size_t)(nbase + m) * H_ + koff;
#pragma unroll
    for (int kc = 0; kc < 4; ++kc) {
        float4 h0 = *(const float4*)(hp + kc * 32);
        float4 h1 = *(const float4*)(hp + kc * 32 + 4);
        float4 t0 = *(const float4*)(tp + kc * 32);
        float4 t1 = *(const float4*)(tp + kc * 32 + 4);
        bf16x8 fh, ft;
        fh[0]=(__bf16)h0.x; fh[1]=(__bf16)h0.y; fh[2]=(__bf16)h0.z; fh[3]=(__bf16)h0.w;
        fh[4]=(__bf16)h1.x; fh[5]=(__bf16)h1.y; fh[6]=(__bf16)h1.z; fh[7]=(__bf16)h1.w;
        ft[0]=(__bf16)t0.x; ft[1]=(__bf16)t0.y; ft[2]=(__bf16)t0.z; ft[3]=(__bf16)t0.w;
        ft[4]=(__bf16)t1.x; ft[5]=(__bf16)t1.y; ft[6]=(__bf16)t1.z; ft[7]=(__bf16)t1.w;
        a[0 * 4 + kc] = fh;
        a[2 * 4 + kc] = ft;
        short8 s8 = *(const short8*)(ap + kc * 32);
        a[1 * 4 + kc] = __builtin_bit_cast(bf16x8, s8);
    }

    f32x4 acc[8];
#pragma unroll
    for (int nt = 0; nt < 8; ++nt) acc[nt] = (f32x4)0.f;
#pragma unroll
    for (int kc = 0; kc < 12; ++kc) {
#pragma unroll
        for (int nt = 0; nt < 8; ++nt) {
            bf16x8 bf = ldfrag(W1s, kc, nt, lane);
            acc[nt] = __builtin_amdgcn_mfma_f32_16x16x32_bf16(a[kc], bf, acc[nt], 0, 0, 0);
        }
    }

#pragma unroll
    for (int nt = 0; nt < 8; ++nt) {
        int col = nt * 16 + m;
        float bb = b1[col];
#pragma unroll
        for (int r = 0; r < 4; ++r) {
            float v = acc[nt][r] + bb;
            float h = v / (1.f + __expf(-v));
            h1s[wv][q * 4 + r][col] = bf16b(h);
        }
    }

    f32x4 acc2[8];
#pragma unroll
    for (int nt = 0; nt < 8; ++nt) acc2[nt] = (f32x4)0.f;
#pragma unroll
    for (int kc = 0; kc < 4; ++kc) {
        short8 s8 = *(const short8*)&h1s[wv][m][kc * 32 + koff];
        bf16x8 a2 = __builtin_bit_cast(bf16x8, s8);
#pragma unroll
        for (int nt = 0; nt < 8; ++nt) {
            bf16x8 bf = ldfrag(W2s, kc, nt, lane);
            acc2[nt] = __builtin_amdgcn_mfma_f32_16x16x32_bf16(a2, bf, acc2[nt], 0, 0, 0);
        }
    }

    float x[8][4];
#pragma unroll
    for (int nt = 0; nt < 8; ++nt) {
        int col = nt * 16 + m;
        float bb = b2[col];
#pragma unroll
        for (int r = 0; r < 4; ++r) {
            int node = nbase + q * 4 + r;
            x[nt][r] = hidden[node * H_ + col] + acc2[nt][r] + bb;
        }
    }
#pragma unroll
    for (int r = 0; r < 4; ++r) {
        float s = 0.f, ss = 0.f;
#pragma unroll
        for (int nt = 0; nt < 8; ++nt) { s += x[nt][r]; ss += x[nt][r] * x[nt][r]; }
#pragma unroll
        for (int off = 1; off < 16; off <<= 1) {
            s  += __shfl_xor(s, off);
            ss += __shfl_xor(ss, off);
        }
        float mu  = s * (1.f / H_);
        float var = ss * (1.f / H_) - mu * mu;
        float rs  = rsqrtf(var + EPS_);
        int node = nbase + q * 4 + r;
#pragma unroll
        for (int nt = 0; nt < 8; ++nt) {
            int col = nt * 16 + m;
            out[node * H_ + col] = (x[nt][r] - mu) * rs * gamma[col] + beta[col];
        }
    }
}

// ---------------------------------------------------------------------------
extern "C" void kernel_launch(void* const* d_in, const int* in_sizes, int n_in,
                              void* d_out, int out_size, void* d_ws, size_t ws_size,
                              hipStream_t stream)
{
    const float* hidden   = (const float*)d_in[0];
    const float* time_emb = (const float*)d_in[1];
    const int*   eidx     = (const int*)d_in[2];
    const int*   etype    = (const int*)d_in[3];
    const float* edge_emb = (const float*)d_in[4];
    const float* Wq = (const float*)d_in[5];
    const float* bq = (const float*)d_in[6];
    const float* Wk = (const float*)d_in[7];
    const float* bk = (const float*)d_in[8];
    const float* Wv = (const float*)d_in[9];
    const float* bv = (const float*)d_in[10];
    const float* We = (const float*)d_in[11];
    const float* be = (const float*)d_in[12];
    const float* W1 = (const float*)d_in[13];
    const float* b1 = (const float*)d_in[14];
    const float* W2 = (const float*)d_in[15];
    const float* b2 = (const float*)d_in[16];
    const float* gamma = (const float*)d_in[17];
    const float* beta  = (const float*)d_in[18];
    float* out = (float*)d_out;

    constexpr int BNH = B_ * N_ * H_;
    u16* Qb   = (u16*)d_ws;
    u16* Kb   = Qb + BNH;
    u16* Vb   = Kb + BNH;
    u16* aggb = Vb + BNH;
    float* Kt  = (float*)(aggb + BNH);
    float* Vt  = Kt + ET_ * H_;
    float* ebt = Vt + ET_ * H_;
    int* hist   = (int*)(ebt + ET_);
    int* offs   = hist + N_;
    int* cursor = offs + (N_ + 1);
    int* sorted = cursor + N_;
    uintptr_t wp = (uintptr_t)(sorted + E_);
    wp = (wp + 15) & ~(uintptr_t)15;
    u16* W1s = (u16*)wp;
    u16* W2s = W1s + 384 * 128;
    u16* Wqs = W2s + 128 * 128;
    u16* Wks = Wqs + 128 * 128;
    u16* Wvs = Wks + 128 * 128;

    const int* esrc = eidx;
    const int* etgt = eidx + E_;

    hipMemsetAsync(hist, 0, N_ * sizeof(int), stream);

    setup_kernel<<<64 + (E_ + 255) / 256, 256, 0, stream>>>(
        W1, W2, Wq, Wk, Wv, W1s, W2s, Wqs, Wks, Wvs,
        edge_emb, bk, bv, We, be, Kt, Vt, ebt, etgt, hist);
    scan_kernel<<<1, 1024, 0, stream>>>(hist, offs, cursor);
    scatter_qkv_kernel<<<625 + 313, 256, 0, stream>>>(
        esrc, etgt, etype, cursor, sorted,
        hidden, time_emb, Wqs, Wks, Wvs, bq, Qb, Kb, Vb);
    attn_kernel<<<(B_ * N_) / 4, 256, 0, stream>>>(Qb, Kb, Vb, Kt, Vt, ebt, offs, sorted, aggb);
    mlp_mfma_kernel<<<313, 256, 0, stream>>>(hidden, aggb, time_emb, W1s, W2s, b1, b2, gamma, beta, out);
}